// Round 6
// baseline (538.228 us; speedup 1.0000x reference)
//
#include <hip/hip_runtime.h>
#include <hip/hip_bf16.h>

#define LRELU_ALPHA 0.2f

typedef __bf16 bf16x8 __attribute__((ext_vector_type(8)));
typedef __bf16 bf16x4 __attribute__((ext_vector_type(4)));
typedef float f32x4 __attribute__((ext_vector_type(4)));

// Fused: ABf = bf16(a); vall[k] = sum_o a[o*320+k]*a2[o];
// rank[e] = old cnt[src] (atomicAdd return) -- moves the atomic OFF scatter's
// critical path; cnt[src]++ per edge.
__global__ void k_prep_count(const float* __restrict__ a, const float* __restrict__ a2,
                             float* __restrict__ vall, __hip_bfloat16* __restrict__ ABf,
                             const int* __restrict__ e1, int E1,
                             const int* __restrict__ e2, int E2,
                             int* __restrict__ cnt, int* __restrict__ rank) {
    int idx = blockIdx.x * 256 + threadIdx.x;
    if (idx < 128 * 320) ABf[idx] = __float2bfloat16(a[idx]);
    if (idx < 320) {
        float s = 0.f;
#pragma unroll 8
        for (int o = 0; o < 128; ++o) s += a[o * 320 + idx] * a2[o];
        vall[idx] = s;
    }
    if (idx < E1 + E2) {
        int src = (idx < E1) ? e1[idx] : e2[idx - E1];
        rank[idx] = atomicAdd(&cnt[src], 1);
    }
}

// two nodes per wave (32 lanes each): f32x4 loads, 5-level reduce, bf16x4 XBf write.
__global__ void k_node_scores(const float* __restrict__ x, const float* __restrict__ vall,
                              float* __restrict__ s_src, float* __restrict__ s_dst,
                              __hip_bfloat16* __restrict__ XBf, int N) {
    int wid = (int)((blockIdx.x * (size_t)blockDim.x + threadIdx.x) >> 6);
    int lane = threadIdx.x & 63;
    if (wid * 2 >= N) return;
    int half = lane >> 5;
    int j = lane & 31;            // dim block: dims 4j..4j+3
    int n = wid * 2 + half;
    int nc = (n < N) ? n : N - 1;
    f32x4 xv = *reinterpret_cast<const f32x4*>(x + (size_t)nc * 128 + 4 * j);
    if (n < N) {
        bf16x4 xb;
#pragma unroll
        for (int k = 0; k < 4; ++k) xb[k] = (__bf16)xv[k];
        *reinterpret_cast<bf16x4*>(XBf + (size_t)n * 128 + 4 * j) = xb;
    }
    f32x4 vs = *reinterpret_cast<const f32x4*>(vall + 4 * j);
    f32x4 vd = *reinterpret_cast<const f32x4*>(vall + 128 + 4 * j);
    float ps = xv.x * vs.x + xv.y * vs.y + xv.z * vs.z + xv.w * vs.w;
    float pd = xv.x * vd.x + xv.y * vd.y + xv.z * vd.z + xv.w * vd.w;
#pragma unroll
    for (int off = 1; off <= 16; off <<= 1) {
        ps += __shfl_xor(ps, off, 64);
        pd += __shfl_xor(pd, off, 64);
    }
    if (j == 0 && n < N) { s_src[n] = ps; s_dst[n] = pd; }
}

// hierarchical exclusive scan of cnt[N] -> start[N+1]  (proven 3-kernel)
__global__ void k_scan1(const int* __restrict__ cnt, int* __restrict__ bsum, int N) {
    __shared__ int red[256];
    int t = threadIdx.x;
    int idx = blockIdx.x * 256 + t;
    red[t] = (idx < N) ? cnt[idx] : 0;
    __syncthreads();
    for (int off = 128; off > 0; off >>= 1) {
        if (t < off) red[t] += red[t + off];
        __syncthreads();
    }
    if (t == 0) bsum[blockIdx.x] = red[0];
}

__global__ void k_scan2(int* __restrict__ bsum, int nb) {
    __shared__ int tmp[256];
    int t = threadIdx.x;
    int v = (t < nb) ? bsum[t] : 0;
    tmp[t] = v;
    __syncthreads();
    for (int off = 1; off < 256; off <<= 1) {
        int add = (t >= off) ? tmp[t - off] : 0;
        __syncthreads();
        tmp[t] += add;
        __syncthreads();
    }
    if (t < nb) bsum[t] = tmp[t] - v;  // exclusive
}

__global__ void k_scan3(const int* __restrict__ cnt, const int* __restrict__ bsum,
                        int* __restrict__ start, int N, int E) {
    __shared__ int tmp[256];
    int t = threadIdx.x;
    int idx = blockIdx.x * 256 + t;
    int v = (idx < N) ? cnt[idx] : 0;
    tmp[t] = v;
    __syncthreads();
    for (int off = 1; off < 256; off <<= 1) {
        int add = (t >= off) ? tmp[t - off] : 0;
        __syncthreads();
        tmp[t] += add;
        __syncthreads();
    }
    if (idx < N) start[idx] = tmp[t] - v + bsum[blockIdx.x];
    if (blockIdx.x == 0 && t == 0) start[N] = E;
}

// Bucketing with payload relocation + score/exp fusion, ATOMIC-FREE:
// p = start[src] + rank[e] (both cached loads). Per-edge chain is now
// linear-load -> VALU -> store, no serializing atomic round trip.
__global__ void k_scatter_copy(const int* __restrict__ e1, int E1,
                               const int* __restrict__ e2, int E2,
                               const int* __restrict__ rank, const int* __restrict__ start,
                               const float* __restrict__ emb1, const float* __restrict__ emb2,
                               const float* __restrict__ vall,
                               const float* __restrict__ s_src, const float* __restrict__ s_dst,
                               int2* __restrict__ sdt,
                               __hip_bfloat16* __restrict__ embS) {
    int wid = (int)((blockIdx.x * (size_t)blockDim.x + threadIdx.x) >> 6);
    int lane = threadIdx.x & 63;
    int g = lane >> 4, t = lane & 15;
    int e = wid * 4 + g;
    int E = E1 + E2;
    if (e >= E) return;
    int src, dst;
    const float* ep;
    if (e < E1) { src = e1[e]; dst = e1[E1 + e]; ep = emb1 + (size_t)e * 64; }
    else { int q = e - E1; src = e2[q]; dst = e2[E2 + q]; ep = emb2 + (size_t)q * 64; }
    f32x4 em = *reinterpret_cast<const f32x4*>(ep + 4 * t);
    f32x4 r4 = *reinterpret_cast<const f32x4*>(vall + 256 + 4 * t);
    float tv = em.x * r4.x + em.y * r4.y + em.z * r4.z + em.w * r4.w;
#pragma unroll
    for (int off = 1; off <= 8; off <<= 1) tv += __shfl_xor(tv, off, 64);
    // score -> exp, identical op sequence (bit-identical scores)
    float sc = s_src[src] + s_dst[dst] + tv;
    float pz = sc > 0.f ? sc : LRELU_ALPHA * sc;
    float ee = __expf(-pz);
    int p = start[src] + rank[e];
    bf16x4 eb;
#pragma unroll
    for (int k = 0; k < 4; ++k) eb[k] = (__bf16)em[k];
    *reinterpret_cast<bf16x4*>(embS + (size_t)p * 64 + 4 * t) = eb;
    if (t == 0) sdt[p] = make_int2(dst, __float_as_int(ee));
}

// one wave per node, group-parallel (4 groups x 16 lanes, 8 edges/iter).
// Pure weighted accumulation: e_e precomputed in scatter; streams (sdt, embS)
// are linear within the node's segment; XBf reads random but L3-resident.
__global__ void k_gather(const __hip_bfloat16* __restrict__ XBf,
                         const __hip_bfloat16* __restrict__ embS,
                         const int2* __restrict__ sdt,
                         const int* __restrict__ start,
                         __hip_bfloat16* __restrict__ G, float* __restrict__ sxf, int N) {
    int n = (int)((blockIdx.x * (size_t)blockDim.x + threadIdx.x) >> 6);
    int lane = threadIdx.x & 63;
    if (n >= N) return;
    n = __builtin_amdgcn_readfirstlane(n);
    int g = lane >> 4;   // edge slot within a 4-edge batch
    int t = lane & 15;   // lane within group
    int b = start[n], en = start[n + 1];
    f32x4 w4 = {0.f, 0.f, 0.f, 0.f};
    float u8[8] = {0.f, 0.f, 0.f, 0.f, 0.f, 0.f, 0.f, 0.f};
    float rs = 0.f;

    for (int p = b; p < en; p += 8) {
        int q0 = p + g;
        int q1 = p + 4 + g;
        int c0 = (q0 < en) ? q0 : en - 1;   // en > b here, so en-1 valid
        int c1 = (q1 < en) ? q1 : en - 1;
        int2 s0 = sdt[c0], s1 = sdt[c1];
        int d0 = s0.x, d1 = s1.x;
        float e0 = __int_as_float(s0.y);
        float e1v = __int_as_float(s1.y);
        bf16x4 ev0 = *reinterpret_cast<const bf16x4*>(embS + (size_t)c0 * 64 + 4 * t);
        bf16x4 ev1 = *reinterpret_cast<const bf16x4*>(embS + (size_t)c1 * 64 + 4 * t);
        bf16x8 xv0 = *reinterpret_cast<const bf16x8*>(XBf + (size_t)d0 * 128 + 8 * t);
        bf16x8 xv1 = *reinterpret_cast<const bf16x8*>(XBf + (size_t)d1 * 128 + 8 * t);
        if (q0 >= en) e0 = 0.f;
        if (q1 >= en) e1v = 0.f;
        rs += e0 + e1v;
        f32x4 f0 = {(float)ev0[0], (float)ev0[1], (float)ev0[2], (float)ev0[3]};
        f32x4 f1 = {(float)ev1[0], (float)ev1[1], (float)ev1[2], (float)ev1[3]};
        w4 += e0 * f0 + e1v * f1;
#pragma unroll
        for (int j = 0; j < 8; ++j)
            u8[j] += e0 * (float)xv0[j] + e1v * (float)xv1[j];
    }

    // combine the 4 per-group partials (once per node)
#pragma unroll
    for (int j = 0; j < 8; ++j) {
        u8[j] += __shfl_xor(u8[j], 16, 64);
        u8[j] += __shfl_xor(u8[j], 32, 64);
    }
#pragma unroll
    for (int j = 0; j < 4; ++j) {
        w4[j] += __shfl_xor(w4[j], 16, 64);
        w4[j] += __shfl_xor(w4[j], 32, 64);
    }
    rs += __shfl_xor(rs, 16, 64);
    rs += __shfl_xor(rs, 32, 64);

    float inv = (rs == 0.f) ? 0.f : 1.f / rs;
    if (lane < 16) {
        __hip_bfloat16* gp = G + (size_t)n * 192;
        bf16x8 uu;
#pragma unroll
        for (int j = 0; j < 8; ++j) uu[j] = (__bf16)(u8[j] * inv);
        *reinterpret_cast<bf16x8*>(gp + 8 * lane) = uu;
        bf16x4 ww;
#pragma unroll
        for (int j = 0; j < 4; ++j) ww[j] = (__bf16)(w4[j] * inv);
        *reinterpret_cast<bf16x4*>(gp + 128 + 4 * lane) = ww;
        if (lane == 0) sxf[n] = (rs == 0.f) ? 0.f : 1.f;
    }
}

// out[n][o] = elu( sxf[n] * (x[n].a_src[o] + G[n].[a_dst|a_rel][o]) ) via bf16 MFMA.
__global__ __launch_bounds__(256) void k_mfma(
    const __hip_bfloat16* __restrict__ XBf, const __hip_bfloat16* __restrict__ G,
    const __hip_bfloat16* __restrict__ ABf, const float* __restrict__ sxf,
    float* __restrict__ out, int N) {
    int lane = threadIdx.x & 63;
    int wave = threadIdx.x >> 6;
    int m0 = blockIdx.x * 64 + wave * 16;
    int q = lane >> 4, m = lane & 15;
    int rowm = m0 + m; if (rowm >= N) rowm = N - 1;  // clamp; garbage rows never stored
    const __hip_bfloat16* xr = XBf + (size_t)rowm * 128 + q * 8;
    const __hip_bfloat16* gr = G + (size_t)rowm * 192 + q * 8;
    const __hip_bfloat16* br = ABf + (size_t)m * 320 + q * 8;
    f32x4 acc[8];
#pragma unroll
    for (int c = 0; c < 8; ++c) acc[c] = f32x4{0.f, 0.f, 0.f, 0.f};

#pragma unroll
    for (int s = 0; s < 4; ++s) {  // k = s*32 .. +32 from XBf
        bf16x8 af = *reinterpret_cast<const bf16x8*>(xr + s * 32);
#pragma unroll
        for (int c = 0; c < 8; ++c) {
            bf16x8 bf = *reinterpret_cast<const bf16x8*>(br + (size_t)c * 16 * 320 + s * 32);
            acc[c] = __builtin_amdgcn_mfma_f32_16x16x32_bf16(af, bf, acc[c], 0, 0, 0);
        }
    }
#pragma unroll
    for (int s = 0; s < 6; ++s) {  // k = 128 + s*32 .. +32 from G
        bf16x8 af = *reinterpret_cast<const bf16x8*>(gr + s * 32);
#pragma unroll
        for (int c = 0; c < 8; ++c) {
            bf16x8 bf = *reinterpret_cast<const bf16x8*>(br + (size_t)c * 16 * 320 + 128 + s * 32);
            acc[c] = __builtin_amdgcn_mfma_f32_16x16x32_bf16(af, bf, acc[c], 0, 0, 0);
        }
    }

    float sxr[4];
#pragma unroll
    for (int r = 0; r < 4; ++r) {
        int n = m0 + q * 4 + r;
        sxr[r] = (n < N) ? sxf[n] : 0.f;
    }
#pragma unroll
    for (int c = 0; c < 8; ++c) {
#pragma unroll
        for (int r = 0; r < 4; ++r) {
            int n = m0 + q * 4 + r;
            if (n < N) {
                float h = acc[c][r] * sxr[r];
                out[(size_t)n * 128 + c * 16 + m] = h > 0.f ? h : __expf(h) - 1.f;
            }
        }
    }
}

extern "C" void kernel_launch(void* const* d_in, const int* in_sizes, int n_in,
                              void* d_out, int out_size, void* d_ws, size_t ws_size,
                              hipStream_t stream) {
    const float* x    = (const float*)d_in[0];
    const int*   e1   = (const int*)d_in[1];
    const float* emb1 = (const float*)d_in[2];
    const int*   e2   = (const int*)d_in[3];
    const float* emb2 = (const float*)d_in[4];
    const float* a    = (const float*)d_in[5];
    const float* a2   = (const float*)d_in[6];
    float* out = (float*)d_out;

    const int N  = in_sizes[0] / 128;
    const int E1 = in_sizes[1] / 2;
    const int E2 = in_sizes[3] / 2;
    const int E  = E1 + E2;
    const int NB = (N + 255) / 256;  // <=256 (N<=65536)

    // workspace layout
    float* ws    = (float*)d_ws;
    float* vall  = ws;                                   // 512 f
    __hip_bfloat16* ABf = (__hip_bfloat16*)(ws + 512);   // 128*320 bf16 = 20480 f
    float* s_src = ws + 512 + 20480;                     // N
    float* s_dst = s_src + N;                            // N
    float* sxf   = s_dst + N;                            // N
    int*   cnt    = (int*)(sxf + N);                     // N
    int*   bsum   = cnt + N;                             // 256
    int*   start  = bsum + 256;                          // N+1
    int*   rank   = start + N + 1;                       // E
    size_t so = (size_t)((char*)(rank + E) - (char*)d_ws);
    so = (so + 15) & ~(size_t)15;
    int2*  sdt = (int2*)((char*)d_ws + so);              // E int2 (dst, bits(e))
    size_t eo = so + (size_t)E * sizeof(int2);
    eo = (eo + 127) & ~(size_t)127;
    __hip_bfloat16* embS = (__hip_bfloat16*)((char*)d_ws + eo);  // E*64 bf16 = 128 B/row
    size_t xo = eo + (size_t)E * 64 * sizeof(__hip_bfloat16);
    xo = (xo + 15) & ~(size_t)15;
    __hip_bfloat16* XBf = (__hip_bfloat16*)((char*)d_ws + xo);  // N*128 bf16
    size_t go = xo + (size_t)N * 128 * sizeof(__hip_bfloat16);
    go = (go + 15) & ~(size_t)15;
    __hip_bfloat16* G = (__hip_bfloat16*)((char*)d_ws + go);    // N*192 bf16

    size_t needed = go + (size_t)N * 192 * sizeof(__hip_bfloat16);
    if (ws_size < needed) return;  // defensive

    hipMemsetAsync(cnt, 0, (size_t)N * sizeof(int), stream);

    int gridPC = ((E > 128 * 320 ? E : 128 * 320) + 255) / 256;
    k_prep_count<<<gridPC, 256, 0, stream>>>(a, a2, vall, ABf, e1, E1, e2, E2, cnt, rank);
    int W = (N + 1) / 2;  // waves for node_scores (2 nodes/wave)
    k_node_scores<<<(W * 64 + 255) / 256, 256, 0, stream>>>(x, vall, s_src, s_dst, XBf, N);
    k_scan1<<<NB, 256, 0, stream>>>(cnt, bsum, N);
    k_scan2<<<1, 256, 0, stream>>>(bsum, NB);
    k_scan3<<<NB, 256, 0, stream>>>(cnt, bsum, start, N, E);
    int Wsc = (E + 3) / 4;  // waves for scatter_copy (4 edges/wave)
    k_scatter_copy<<<(Wsc * 64 + 255) / 256, 256, 0, stream>>>(
        e1, E1, e2, E2, rank, start, emb1, emb2, vall, s_src, s_dst, sdt, embS);
    k_gather<<<(N * 64 + 255) / 256, 256, 0, stream>>>(
        XBf, embS, sdt, start, G, sxf, N);
    k_mfma<<<(N + 63) / 64, 256, 0, stream>>>(XBf, G, ABf, sxf, out, N);
}

// Round 7
// 531.044 us; speedup vs baseline: 1.0135x; 1.0135x over previous
//
#include <hip/hip_runtime.h>
#include <hip/hip_bf16.h>

#define LRELU_ALPHA 0.2f

typedef __bf16 bf16x8 __attribute__((ext_vector_type(8)));
typedef __bf16 bf16x4 __attribute__((ext_vector_type(4)));
typedef float f32x4 __attribute__((ext_vector_type(4)));

// Fused: ABf = bf16(a); vall[k] = sum_o a[o*320+k]*a2[o]; cnt[src]++ per edge.
__global__ void k_prep_count(const float* __restrict__ a, const float* __restrict__ a2,
                             float* __restrict__ vall, __hip_bfloat16* __restrict__ ABf,
                             const int* __restrict__ e1, int E1,
                             const int* __restrict__ e2, int E2, int* __restrict__ cnt) {
    int idx = blockIdx.x * 256 + threadIdx.x;
    if (idx < 128 * 320) ABf[idx] = __float2bfloat16(a[idx]);
    if (idx < 320) {
        float s = 0.f;
#pragma unroll 8
        for (int o = 0; o < 128; ++o) s += a[o * 320 + idx] * a2[o];
        vall[idx] = s;
    }
    if (idx < E1 + E2) {
        int src = (idx < E1) ? e1[idx] : e2[idx - E1];
        atomicAdd(&cnt[src], 1);
    }
}

// two nodes per wave (32 lanes each): f32x4 loads, 5-level reduce, bf16x4 XBf write.
__global__ void k_node_scores(const float* __restrict__ x, const float* __restrict__ vall,
                              float* __restrict__ s_src, float* __restrict__ s_dst,
                              __hip_bfloat16* __restrict__ XBf, int N) {
    int wid = (int)((blockIdx.x * (size_t)blockDim.x + threadIdx.x) >> 6);
    int lane = threadIdx.x & 63;
    if (wid * 2 >= N) return;
    int half = lane >> 5;
    int j = lane & 31;            // dim block: dims 4j..4j+3
    int n = wid * 2 + half;
    int nc = (n < N) ? n : N - 1;
    f32x4 xv = *reinterpret_cast<const f32x4*>(x + (size_t)nc * 128 + 4 * j);
    if (n < N) {
        bf16x4 xb;
#pragma unroll
        for (int k = 0; k < 4; ++k) xb[k] = (__bf16)xv[k];
        *reinterpret_cast<bf16x4*>(XBf + (size_t)n * 128 + 4 * j) = xb;
    }
    f32x4 vs = *reinterpret_cast<const f32x4*>(vall + 4 * j);
    f32x4 vd = *reinterpret_cast<const f32x4*>(vall + 128 + 4 * j);
    float ps = xv.x * vs.x + xv.y * vs.y + xv.z * vs.z + xv.w * vs.w;
    float pd = xv.x * vd.x + xv.y * vd.y + xv.z * vd.z + xv.w * vd.w;
#pragma unroll
    for (int off = 1; off <= 16; off <<= 1) {
        ps += __shfl_xor(ps, off, 64);
        pd += __shfl_xor(pd, off, 64);
    }
    if (j == 0 && n < N) { s_src[n] = ps; s_dst[n] = pd; }
}

// hierarchical exclusive scan of cnt[N] -> start[N+1], cursor[N]  (proven 3-kernel)
__global__ void k_scan1(const int* __restrict__ cnt, int* __restrict__ bsum, int N) {
    __shared__ int red[256];
    int t = threadIdx.x;
    int idx = blockIdx.x * 256 + t;
    red[t] = (idx < N) ? cnt[idx] : 0;
    __syncthreads();
    for (int off = 128; off > 0; off >>= 1) {
        if (t < off) red[t] += red[t + off];
        __syncthreads();
    }
    if (t == 0) bsum[blockIdx.x] = red[0];
}

__global__ void k_scan2(int* __restrict__ bsum, int nb) {
    __shared__ int tmp[256];
    int t = threadIdx.x;
    int v = (t < nb) ? bsum[t] : 0;
    tmp[t] = v;
    __syncthreads();
    for (int off = 1; off < 256; off <<= 1) {
        int add = (t >= off) ? tmp[t - off] : 0;
        __syncthreads();
        tmp[t] += add;
        __syncthreads();
    }
    if (t < nb) bsum[t] = tmp[t] - v;  // exclusive
}

__global__ void k_scan3(const int* __restrict__ cnt, const int* __restrict__ bsum,
                        int* __restrict__ start, int* __restrict__ cursor, int N, int E) {
    __shared__ int tmp[256];
    int t = threadIdx.x;
    int idx = blockIdx.x * 256 + t;
    int v = (idx < N) ? cnt[idx] : 0;
    tmp[t] = v;
    __syncthreads();
    for (int off = 1; off < 256; off <<= 1) {
        int add = (t >= off) ? tmp[t - off] : 0;
        __syncthreads();
        tmp[t] += add;
        __syncthreads();
    }
    if (idx < N) {
        int excl = tmp[t] - v + bsum[blockIdx.x];
        start[idx] = excl;
        cursor[idx] = excl;
    }
    if (blockIdx.x == 0 && t == 0) start[N] = E;
}

// Bucketing WITH payload relocation + full score/exp fusion: one 16-lane group
// per edge. Linear reads (edges, emb rows f32x4/lane); L3-resident reads
// (s_src[src], s_dst[dst]); random writes: 128 B embS row (one full line) +
// ONE packed int2 (dst, float_bits(e)) -> one 64 B sector per edge.
// NOTE (r6): atomic-free variant (rank precomputed in prep_count) measured
// IDENTICAL (124 vs 123 us) with +12 MB traffic elsewhere -> the atomic is NOT
// binding; the ~123 us is the 1M-random-row-touch floor. Reverted.
__global__ void k_scatter_copy(const int* __restrict__ e1, int E1,
                               const int* __restrict__ e2, int E2,
                               int* __restrict__ cursor,
                               const float* __restrict__ emb1, const float* __restrict__ emb2,
                               const float* __restrict__ vall,
                               const float* __restrict__ s_src, const float* __restrict__ s_dst,
                               int2* __restrict__ sdt,
                               __hip_bfloat16* __restrict__ embS) {
    int wid = (int)((blockIdx.x * (size_t)blockDim.x + threadIdx.x) >> 6);
    int lane = threadIdx.x & 63;
    int g = lane >> 4, t = lane & 15;
    int e = wid * 4 + g;
    int E = E1 + E2;
    if (e >= E) return;
    int src, dst;
    const float* ep;
    if (e < E1) { src = e1[e]; dst = e1[E1 + e]; ep = emb1 + (size_t)e * 64; }
    else { int q = e - E1; src = e2[q]; dst = e2[E2 + q]; ep = emb2 + (size_t)q * 64; }
    f32x4 em = *reinterpret_cast<const f32x4*>(ep + 4 * t);
    f32x4 r4 = *reinterpret_cast<const f32x4*>(vall + 256 + 4 * t);
    float tv = em.x * r4.x + em.y * r4.y + em.z * r4.z + em.w * r4.w;
#pragma unroll
    for (int off = 1; off <= 8; off <<= 1) tv += __shfl_xor(tv, off, 64);
    // score -> exp, identical op sequence to the original gather (bit-identical)
    float sc = s_src[src] + s_dst[dst] + tv;
    float pz = sc > 0.f ? sc : LRELU_ALPHA * sc;
    float ee = __expf(-pz);
    int p = 0;
    if (t == 0) p = atomicAdd(&cursor[src], 1);
    p = __shfl(p, g * 16, 64);  // broadcast from group leader
    bf16x4 eb;
#pragma unroll
    for (int k = 0; k < 4; ++k) eb[k] = (__bf16)em[k];
    *reinterpret_cast<bf16x4*>(embS + (size_t)p * 64 + 4 * t) = eb;
    if (t == 0) sdt[p] = make_int2(dst, __float_as_int(ee));
}

// one wave per node, group-parallel (4 groups x 16 lanes, 8 edges/iter).
// Pure weighted accumulation: e_e precomputed in scatter; streams (sdt, embS)
// are linear within the node's segment; XBf reads random but L3-resident.
__global__ void k_gather(const __hip_bfloat16* __restrict__ XBf,
                         const __hip_bfloat16* __restrict__ embS,
                         const int2* __restrict__ sdt,
                         const int* __restrict__ start,
                         __hip_bfloat16* __restrict__ G, float* __restrict__ sxf, int N) {
    int n = (int)((blockIdx.x * (size_t)blockDim.x + threadIdx.x) >> 6);
    int lane = threadIdx.x & 63;
    if (n >= N) return;
    n = __builtin_amdgcn_readfirstlane(n);
    int g = lane >> 4;   // edge slot within a 4-edge batch
    int t = lane & 15;   // lane within group
    int b = start[n], en = start[n + 1];
    f32x4 w4 = {0.f, 0.f, 0.f, 0.f};
    float u8[8] = {0.f, 0.f, 0.f, 0.f, 0.f, 0.f, 0.f, 0.f};
    float rs = 0.f;

    for (int p = b; p < en; p += 8) {
        int q0 = p + g;
        int q1 = p + 4 + g;
        int c0 = (q0 < en) ? q0 : en - 1;   // en > b here, so en-1 valid
        int c1 = (q1 < en) ? q1 : en - 1;
        int2 s0 = sdt[c0], s1 = sdt[c1];
        int d0 = s0.x, d1 = s1.x;
        float e0 = __int_as_float(s0.y);
        float e1v = __int_as_float(s1.y);
        bf16x4 ev0 = *reinterpret_cast<const bf16x4*>(embS + (size_t)c0 * 64 + 4 * t);
        bf16x4 ev1 = *reinterpret_cast<const bf16x4*>(embS + (size_t)c1 * 64 + 4 * t);
        bf16x8 xv0 = *reinterpret_cast<const bf16x8*>(XBf + (size_t)d0 * 128 + 8 * t);
        bf16x8 xv1 = *reinterpret_cast<const bf16x8*>(XBf + (size_t)d1 * 128 + 8 * t);
        if (q0 >= en) e0 = 0.f;
        if (q1 >= en) e1v = 0.f;
        rs += e0 + e1v;
        f32x4 f0 = {(float)ev0[0], (float)ev0[1], (float)ev0[2], (float)ev0[3]};
        f32x4 f1 = {(float)ev1[0], (float)ev1[1], (float)ev1[2], (float)ev1[3]};
        w4 += e0 * f0 + e1v * f1;
#pragma unroll
        for (int j = 0; j < 8; ++j)
            u8[j] += e0 * (float)xv0[j] + e1v * (float)xv1[j];
    }

    // combine the 4 per-group partials (once per node)
#pragma unroll
    for (int j = 0; j < 8; ++j) {
        u8[j] += __shfl_xor(u8[j], 16, 64);
        u8[j] += __shfl_xor(u8[j], 32, 64);
    }
#pragma unroll
    for (int j = 0; j < 4; ++j) {
        w4[j] += __shfl_xor(w4[j], 16, 64);
        w4[j] += __shfl_xor(w4[j], 32, 64);
    }
    rs += __shfl_xor(rs, 16, 64);
    rs += __shfl_xor(rs, 32, 64);

    float inv = (rs == 0.f) ? 0.f : 1.f / rs;
    if (lane < 16) {
        __hip_bfloat16* gp = G + (size_t)n * 192;
        bf16x8 uu;
#pragma unroll
        for (int j = 0; j < 8; ++j) uu[j] = (__bf16)(u8[j] * inv);
        *reinterpret_cast<bf16x8*>(gp + 8 * lane) = uu;
        bf16x4 ww;
#pragma unroll
        for (int j = 0; j < 4; ++j) ww[j] = (__bf16)(w4[j] * inv);
        *reinterpret_cast<bf16x4*>(gp + 128 + 4 * lane) = ww;
        if (lane == 0) sxf[n] = (rs == 0.f) ? 0.f : 1.f;
    }
}

// out[n][o] = elu( sxf[n] * (x[n].a_src[o] + G[n].[a_dst|a_rel][o]) ) via bf16 MFMA.
__global__ __launch_bounds__(256) void k_mfma(
    const __hip_bfloat16* __restrict__ XBf, const __hip_bfloat16* __restrict__ G,
    const __hip_bfloat16* __restrict__ ABf, const float* __restrict__ sxf,
    float* __restrict__ out, int N) {
    int lane = threadIdx.x & 63;
    int wave = threadIdx.x >> 6;
    int m0 = blockIdx.x * 64 + wave * 16;
    int q = lane >> 4, m = lane & 15;
    int rowm = m0 + m; if (rowm >= N) rowm = N - 1;  // clamp; garbage rows never stored
    const __hip_bfloat16* xr = XBf + (size_t)rowm * 128 + q * 8;
    const __hip_bfloat16* gr = G + (size_t)rowm * 192 + q * 8;
    const __hip_bfloat16* br = ABf + (size_t)m * 320 + q * 8;
    f32x4 acc[8];
#pragma unroll
    for (int c = 0; c < 8; ++c) acc[c] = f32x4{0.f, 0.f, 0.f, 0.f};

#pragma unroll
    for (int s = 0; s < 4; ++s) {  // k = s*32 .. +32 from XBf
        bf16x8 af = *reinterpret_cast<const bf16x8*>(xr + s * 32);
#pragma unroll
        for (int c = 0; c < 8; ++c) {
            bf16x8 bf = *reinterpret_cast<const bf16x8*>(br + (size_t)c * 16 * 320 + s * 32);
            acc[c] = __builtin_amdgcn_mfma_f32_16x16x32_bf16(af, bf, acc[c], 0, 0, 0);
        }
    }
#pragma unroll
    for (int s = 0; s < 6; ++s) {  // k = 128 + s*32 .. +32 from G
        bf16x8 af = *reinterpret_cast<const bf16x8*>(gr + s * 32);
#pragma unroll
        for (int c = 0; c < 8; ++c) {
            bf16x8 bf = *reinterpret_cast<const bf16x8*>(br + (size_t)c * 16 * 320 + 128 + s * 32);
            acc[c] = __builtin_amdgcn_mfma_f32_16x16x32_bf16(af, bf, acc[c], 0, 0, 0);
        }
    }

    float sxr[4];
#pragma unroll
    for (int r = 0; r < 4; ++r) {
        int n = m0 + q * 4 + r;
        sxr[r] = (n < N) ? sxf[n] : 0.f;
    }
#pragma unroll
    for (int c = 0; c < 8; ++c) {
#pragma unroll
        for (int r = 0; r < 4; ++r) {
            int n = m0 + q * 4 + r;
            if (n < N) {
                float h = acc[c][r] * sxr[r];
                out[(size_t)n * 128 + c * 16 + m] = h > 0.f ? h : __expf(h) - 1.f;
            }
        }
    }
}

extern "C" void kernel_launch(void* const* d_in, const int* in_sizes, int n_in,
                              void* d_out, int out_size, void* d_ws, size_t ws_size,
                              hipStream_t stream) {
    const float* x    = (const float*)d_in[0];
    const int*   e1   = (const int*)d_in[1];
    const float* emb1 = (const float*)d_in[2];
    const int*   e2   = (const int*)d_in[3];
    const float* emb2 = (const float*)d_in[4];
    const float* a    = (const float*)d_in[5];
    const float* a2   = (const float*)d_in[6];
    float* out = (float*)d_out;

    const int N  = in_sizes[0] / 128;
    const int E1 = in_sizes[1] / 2;
    const int E2 = in_sizes[3] / 2;
    const int E  = E1 + E2;
    const int NB = (N + 255) / 256;  // <=256 (N<=65536)

    // workspace layout
    float* ws    = (float*)d_ws;
    float* vall  = ws;                                   // 512 f
    __hip_bfloat16* ABf = (__hip_bfloat16*)(ws + 512);   // 128*320 bf16 = 20480 f
    float* s_src = ws + 512 + 20480;                     // N
    float* s_dst = s_src + N;                            // N
    float* sxf   = s_dst + N;                            // N
    int*   cnt    = (int*)(sxf + N);                     // N
    int*   bsum   = cnt + N;                             // 256
    int*   start  = bsum + 256;                          // N+1
    int*   cursor = start + N + 1;                       // N+1
    size_t so = (size_t)((char*)(cursor + N + 1) - (char*)d_ws);
    so = (so + 15) & ~(size_t)15;
    int2*  sdt = (int2*)((char*)d_ws + so);              // E int2 (dst, bits(e))
    size_t eo = so + (size_t)E * sizeof(int2);
    eo = (eo + 127) & ~(size_t)127;
    __hip_bfloat16* embS = (__hip_bfloat16*)((char*)d_ws + eo);  // E*64 bf16 = 128 B/row
    size_t xo = eo + (size_t)E * 64 * sizeof(__hip_bfloat16);
    xo = (xo + 15) & ~(size_t)15;
    __hip_bfloat16* XBf = (__hip_bfloat16*)((char*)d_ws + xo);  // N*128 bf16
    size_t go = xo + (size_t)N * 128 * sizeof(__hip_bfloat16);
    go = (go + 15) & ~(size_t)15;
    __hip_bfloat16* G = (__hip_bfloat16*)((char*)d_ws + go);    // N*192 bf16

    size_t needed = go + (size_t)N * 192 * sizeof(__hip_bfloat16);
    if (ws_size < needed) return;  // defensive

    hipMemsetAsync(cnt, 0, (size_t)N * sizeof(int), stream);

    int gridPC = ((E > 128 * 320 ? E : 128 * 320) + 255) / 256;
    k_prep_count<<<gridPC, 256, 0, stream>>>(a, a2, vall, ABf, e1, E1, e2, E2, cnt);
    int W = (N + 1) / 2;  // waves for node_scores (2 nodes/wave)
    k_node_scores<<<(W * 64 + 255) / 256, 256, 0, stream>>>(x, vall, s_src, s_dst, XBf, N);
    k_scan1<<<NB, 256, 0, stream>>>(cnt, bsum, N);
    k_scan2<<<1, 256, 0, stream>>>(bsum, NB);
    k_scan3<<<NB, 256, 0, stream>>>(cnt, bsum, start, cursor, N, E);
    int Wsc = (E + 3) / 4;  // waves for scatter_copy (4 edges/wave)
    k_scatter_copy<<<(Wsc * 64 + 255) / 256, 256, 0, stream>>>(
        e1, E1, e2, E2, cursor, emb1, emb2, vall, s_src, s_dst, sdt, embS);
    k_gather<<<(N * 64 + 255) / 256, 256, 0, stream>>>(
        XBf, embS, sdt, start, G, sxf, N);
    k_mfma<<<(N + 63) / 64, 256, 0, stream>>>(XBf, G, ABf, sxf, out, N);
}